// Round 16
// baseline (269.842 us; speedup 1.0000x reference)
//
#include <hip/hip_runtime.h>
#include <stdint.h>

#define FDIM 64
#define BINSH 6
#define NBINS 1563         // ceil(100000 / 64)
#define BCAP 1536          // bin capacity; mean 1024, sigma ~32 -> 16 sigma margin
#define LCAP 1184          // half-bin CSR capacity
#define OVCAP 8192         // overflow-edge capacity (expected usage: 0)
#define PSTAGE 4096        // edges staged per k_part block
#define GGRID 2048         // gather grid = exact residency (8 blocks/CU x 256)

// ---------- sentinel ----------
__global__ __launch_bounds__(256) void k_sentinel(float* out, int N, float val) {
    int n = blockIdx.x * 256 + threadIdx.x;
    if (n < N) out[n] = (n == 0) ? val : 0.f;
}

// ---------- 1. GRU weight evolution: W = (1-z)*n + z*W0 ----------
__global__ __launch_bounds__(64) void k_evolve(
    const float* __restrict__ W0, const float* __restrict__ Wi,
    const float* __restrict__ Wh, const float* __restrict__ bi,
    const float* __restrict__ bh, float* __restrict__ W) {
    int i = blockIdx.x;
    int j = threadIdx.x;
    __shared__ float w0s[64];
    w0s[j] = W0[i * 64 + j];
    __syncthreads();
    float a0 = 0.f, a1 = 0.f, a2 = 0.f, b0 = 0.f, b1 = 0.f, b2 = 0.f;
#pragma unroll 8
    for (int k = 0; k < 64; k++) {
        float w0k = w0s[k];
        a0 += w0k * Wi[(j)       * 64 + k];
        a1 += w0k * Wi[(64 + j)  * 64 + k];
        a2 += w0k * Wi[(128 + j) * 64 + k];
        b0 += w0k * Wh[(j)       * 64 + k];
        b1 += w0k * Wh[(64 + j)  * 64 + k];
        b2 += w0k * Wh[(128 + j) * 64 + k];
    }
    float ir = a0 + bi[j],        hr = b0 + bh[j];
    float iz = a1 + bi[64 + j],   hz = b1 + bh[64 + j];
    float in_ = a2 + bi[128 + j], hn = b2 + bh[128 + j];
    float r = 1.f / (1.f + expf(-(ir + hr)));
    float z = 1.f / (1.f + expf(-(iz + hz)));
    float n = tanhf(in_ + r * hn);
    W[i * 64 + j] = (1.f - z) * n + z * w0s[j];
}

// ---------- 2. MT[j][k] = (W @ projW^T)[k][j] ----------
__global__ __launch_bounds__(64) void k_matM(
    const float* __restrict__ W, const float* __restrict__ projW,
    float* __restrict__ MT) {
    int k = blockIdx.x;
    int j = threadIdx.x;
    __shared__ float wr[64];
    wr[j] = W[k * 64 + j];
    __syncthreads();
    float s = 0.f;
#pragma unroll 8
    for (int q = 0; q < 64; q++) s += wr[q] * projW[j * 64 + q];
    MT[j * 64 + k] = s;
}

// ---------- 3. partition: LDS counting sort by bin -> contiguous run writes ----------
__global__ __launch_bounds__(1024) void k_part(
    const int* __restrict__ src, const int* __restrict__ dst,
    const float* __restrict__ ew, int* __restrict__ gcnt,
    int2* __restrict__ part, int* __restrict__ ovf_cnt,
    int* __restrict__ ovs, int* __restrict__ ovd, float* __restrict__ ovw,
    int E) {
    __shared__ int  hist[NBINS];
    __shared__ int  scn[NBINS];
    __shared__ int  lcur[NBINS];
    __shared__ int2 stage[PSTAGE];
    __shared__ unsigned short sbin[PSTAGE];
    int t = threadIdx.x;
    for (int b = t; b < NBINS; b += 1024) hist[b] = 0;
    __syncthreads();
    int e0 = blockIdx.x * PSTAGE;
    int cnt = E - e0; if (cnt > PSTAGE) cnt = PSTAGE;
    for (int i = t; i < cnt; i += 1024) atomicAdd(&hist[dst[e0 + i] >> BINSH], 1);
    __syncthreads();
    for (int b = t; b < NBINS; b += 1024) scn[b] = hist[b];
    __syncthreads();
    for (int off = 1; off < NBINS; off <<= 1) {
        int i1 = t, i2 = t + 1024;
        int a1 = (i1 < NBINS && i1 >= off) ? scn[i1 - off] : 0;
        int a2 = (i2 < NBINS && i2 >= off) ? scn[i2 - off] : 0;
        __syncthreads();
        if (i1 < NBINS) scn[i1] += a1;
        if (i2 < NBINS) scn[i2] += a2;
        __syncthreads();
    }
    for (int b = t; b < NBINS; b += 1024) {
        int h = hist[b];
        int lbase = scn[b] - h;
        int gb = h ? atomicAdd(&gcnt[b], h) : 0;
        lcur[b] = lbase;
        hist[b] = gb - lbase;
    }
    __syncthreads();
    for (int i = t; i < cnt; i += 1024) {
        int e = e0 + i;
        int d = dst[e];
        int b = d >> BINSH;
        int p = atomicAdd(&lcur[b], 1);
        stage[p] = make_int2(src[e] | ((d & 63) << 20), __float_as_int(ew[e]));
        sbin[p] = (unsigned short)b;
    }
    __syncthreads();
    for (int i = t; i < cnt; i += 1024) {
        int b = sbin[i];
        int2 e = stage[i];
        int p = i + hist[b];
        if (p < BCAP) {
            part[(size_t)b * BCAP + p] = e;
        } else {
            int op = atomicAdd(ovf_cnt, 1);
            if (op < OVCAP) {
                ovs[op] = e.x & 0xFFFFF;
                ovd[op] = (b << BINSH) | ((e.x >> 20) & 63);
                ovw[op] = __int_as_float(e.y);
            }
        }
    }
}

// ---------- 4. deg + dinv per bin; ovf entries folded in (normally none) ----------
__global__ __launch_bounds__(256) void k_deg2(
    const int* __restrict__ gcnt, const int2* __restrict__ part,
    const int* __restrict__ ovf_cnt, const int* __restrict__ ovd,
    const float* __restrict__ ovw,
    float* __restrict__ deg, float* __restrict__ dinv, int N) {
    __shared__ float dl[64];
    int t = threadIdx.x, b = blockIdx.x;
    if (t < 64) dl[t] = 1.0f;   // self-loop
    __syncthreads();
    int c = gcnt[b]; if (c > BCAP) c = BCAP;
    const int2* pe = part + (size_t)b * BCAP;
    for (int i = t; i < c; i += 256) {
        int2 e = pe[i];
        atomicAdd(&dl[(e.x >> 20) & 63], __int_as_float(e.y));
    }
    int m = *ovf_cnt; if (m > OVCAP) m = OVCAP;   // normally 0
    for (int i = t; i < m; i += 256) {
        int d = ovd[i];
        if ((d >> BINSH) == b) atomicAdd(&dl[d & 63], ovw[i]);
    }
    __syncthreads();
    int n = b * 64 + t;
    if (t < 64 && n < N) {
        float d = dl[t];
        deg[n] = d;
        dinv[n] = d > 0.f ? rsqrtf(d) : 0.f;
    }
}

// ---------- 5. gather: work-stealing over 2*NBINS half-bin tasks ----------
__global__ __launch_bounds__(256) void k_gather2(
    const float* __restrict__ x, const float* __restrict__ dinv,
    const int* __restrict__ gcnt, const int2* __restrict__ part,
    float* __restrict__ agg, int* __restrict__ ticket, int* __restrict__ ovf_cnt,
    int* __restrict__ ovs, int* __restrict__ ovd, float* __restrict__ ovw,
    int N) {
    __shared__ int  task_s;
    __shared__ int  lcnt[32];
    __shared__ int  loff[33];
    __shared__ int  lcur[32];
    __shared__ int2 ledge[LCAP];
    int t = threadIdx.x;
    while (true) {
        __syncthreads();   // protect LDS reuse + task_s from prior iteration
        if (t == 0) task_s = atomicAdd(ticket, 1);
        __syncthreads();
        int task = task_s;
        if (task >= 2 * NBINS) return;
        int bb = task >> 1;    // bin
        int hh = task & 1;     // half: nodes [hh*32, hh*32+32)
        if (t < 32) lcnt[t] = 0;
        __syncthreads();
        int c = gcnt[bb]; if (c > BCAP) c = BCAP;
        const int2* pe = part + (size_t)bb * BCAP;
        for (int i = t; i < c; i += 256) {
            int nl = (pe[i].x >> 20) & 63;
            if ((nl >> 5) == hh) atomicAdd(&lcnt[nl & 31], 1);
        }
        __syncthreads();
        if (t == 0) {
            int o = 0;
#pragma unroll 8
            for (int k = 0; k < 32; k++) { loff[k] = o; o += lcnt[k]; }
            loff[32] = o;
        }
        __syncthreads();
        if (t < 32) lcur[t] = loff[t];
        __syncthreads();
        for (int i = t; i < c; i += 256) {
            int2 e = pe[i];
            int nl = (e.x >> 20) & 63;
            if ((nl >> 5) != hh) continue;
            int p = atomicAdd(&lcur[nl & 31], 1);
            if (p < LCAP) {
                ledge[p] = e;
            } else {  // ~30-sigma event; patched by k_head's ovf scan
                int op = atomicAdd(ovf_cnt, 1);
                if (op < OVCAP) {
                    ovs[op] = e.x & 0xFFFFF;
                    ovd[op] = (bb << BINSH) | nl;
                    ovw[op] = __int_as_float(e.y);
                }
            }
        }
        __syncthreads();
        int wv = t >> 6, lane = t & 63, eg = lane >> 4, f = (lane & 15) * 4;
        for (int nlh = wv; nlh < 32; nlh += 4) {
            int n = bb * 64 + hh * 32 + nlh;
            if (n >= N) continue;
            float dn = dinv[n];
            int beg = loff[nlh], end = loff[nlh + 1];
            if (beg > LCAP) beg = LCAP;
            if (end > LCAP) end = LCAP;
            float ax = 0.f, ay = 0.f, az = 0.f, aw = 0.f;
            for (int i = beg + eg; i < end; i += 4) {
                int2 e = ledge[i];
                int s = e.x & 0xFFFFF;
                float nm = dinv[s] * __int_as_float(e.y) * dn;
                float4 xv = *(const float4*)&x[(size_t)s * 64 + f];
                ax += nm * xv.x; ay += nm * xv.y; az += nm * xv.z; aw += nm * xv.w;
            }
            ax += __shfl_xor(ax, 16); ay += __shfl_xor(ay, 16);
            az += __shfl_xor(az, 16); aw += __shfl_xor(aw, 16);
            ax += __shfl_xor(ax, 32); ay += __shfl_xor(ay, 32);
            az += __shfl_xor(az, 32); aw += __shfl_xor(aw, 32);
            if (eg == 0) {
                float sl = dn * dn;
                float4 xv = *(const float4*)&x[(size_t)n * 64 + f];  // self-loop
                float4 o = make_float4(ax + sl * xv.x, ay + sl * xv.y,
                                       az + sl * xv.z, aw + sl * xv.w);
                *(float4*)&agg[(size_t)n * 64 + f] = o;
            }
        }
    }
}

// ---------- 6. head: out = relu(agg @ M + pb) @ linW^T + lb ; ovf patched in ----------
__global__ __launch_bounds__(256) void k_head(
    const float* __restrict__ agg, const float* __restrict__ MT,
    const float* __restrict__ projB, const float* __restrict__ linW,
    const float* __restrict__ linB, const float* __restrict__ x,
    const float* __restrict__ dinv, const int* __restrict__ ovf_cnt,
    const int* __restrict__ ovs, const int* __restrict__ ovd,
    const float* __restrict__ ovw, float* __restrict__ out, int N) {
    __shared__ float hs[64 * 68];
    __shared__ float ps[64 * 68];
    __shared__ float red[64 * 17];
    __shared__ float pbs[64], lws[64];
    int t  = threadIdx.x;
    int nb = blockIdx.x * 64;
#pragma unroll
    for (int i = 0; i < 4; i++) {
        int lin = i * 1024 + t * 4;
        int row = lin >> 6, col = lin & 63;
        int node = nb + row;
        float4 v = make_float4(0.f, 0.f, 0.f, 0.f);
        if (node < N) v = *(const float4*)(agg + (size_t)node * 64 + col);
        *(float4*)&hs[row * 68 + col] = v;
        *(float4*)&ps[row * 68 + col] = *(const float4*)(MT + lin);
    }
    if (t < 64) { pbs[t] = projB[t]; lws[t] = linW[t]; }
    __syncthreads();
    // ovf patch for this 64-node tile (normally m==0 -> one scalar read)
    int m = *ovf_cnt; if (m > OVCAP) m = OVCAP;
    for (int i = t; i < m; i += 256) {
        int d = ovd[i];
        if ((d >> BINSH) == blockIdx.x && d < N) {
            int s = ovs[i];
            float nm = dinv[s] * ovw[i] * dinv[d];
            int nl = d & 63;
            for (int ff = 0; ff < 64; ff++)
                atomicAdd(&hs[nl * 68 + ff], nm * x[(size_t)s * 64 + ff]);
        }
    }
    if (m) __syncthreads();
    int tj = t & 15, tn = t >> 4;
    float acc[4][4] = {};
    for (int k = 0; k < 64; k += 4) {
        float4 hv[4], pv[4];
#pragma unroll
        for (int nn = 0; nn < 4; nn++) hv[nn] = *(const float4*)&hs[(tn * 4 + nn) * 68 + k];
#pragma unroll
        for (int jj = 0; jj < 4; jj++) pv[jj] = *(const float4*)&ps[(tj * 4 + jj) * 68 + k];
#pragma unroll
        for (int nn = 0; nn < 4; nn++) {
            const float* hp = (const float*)&hv[nn];
#pragma unroll
            for (int jj = 0; jj < 4; jj++) {
                const float* pp = (const float*)&pv[jj];
                acc[nn][jj] += hp[0] * pp[0] + hp[1] * pp[1] + hp[2] * pp[2] + hp[3] * pp[3];
            }
        }
    }
    float lb = linB[0];
#pragma unroll
    for (int nn = 0; nn < 4; nn++) {
        float s = 0.f;
#pragma unroll
        for (int jj = 0; jj < 4; jj++) {
            int j = tj * 4 + jj;
            float v = acc[nn][jj] + pbs[j];
            v = v > 0.f ? v : 0.f;
            s += v * lws[j];
        }
        red[(tn * 4 + nn) * 17 + tj] = s;
    }
    __syncthreads();
    if (t < 64) {
        float s = lb;
#pragma unroll
        for (int q = 0; q < 16; q++) s += red[t * 17 + q];
        int node = nb + t;
        if (node < N) out[node] = s;
    }
}

extern "C" void kernel_launch(void* const* d_in, const int* in_sizes, int n_in,
                              void* d_out, int out_size, void* d_ws, size_t ws_size,
                              hipStream_t stream) {
    const float* x   = (const float*)d_in[0];
    const int*   ei  = (const int*)d_in[1];
    const float* ew  = (const float*)d_in[2];
    const float* W0  = (const float*)d_in[3];
    const float* gWi = (const float*)d_in[4];
    const float* gWh = (const float*)d_in[5];
    const float* gbi = (const float*)d_in[6];
    const float* gbh = (const float*)d_in[7];
    const float* pW  = (const float*)d_in[8];
    const float* pb  = (const float*)d_in[9];
    const float* lW  = (const float*)d_in[10];
    const float* lb  = (const float*)d_in[11];
    float* out = (float*)d_out;

    static const int EXPSZ[12] = {6400000, 3200000, 1600000, 4096, 12288, 12288,
                                  192, 192, 4096, 64, 64, 1};
    int mism = -1;
    for (int i = 0; i < 12 && i < n_in; i++)
        if (in_sizes[i] != EXPSZ[i]) { mism = i; break; }
    if (mism >= 0) {
        k_sentinel<<<(out_size + 255) / 256, 256, 0, stream>>>(out, out_size,
                                                               ldexpf(1.f, 30 + 3 * mism));
        return;
    }

    int N = in_sizes[0] / FDIM;          // 100000
    int E = in_sizes[1] / 2;             // 1600000
    const int* src = ei;
    const int* dst = ei + E;

    // ws layout (bytes):
    //  0     W 16 KB | 16K MT 16 KB
    //  32K   gcnt 6.3 KB | 39K ovf_cnt 4 B | 39K+64 ticket 4 B   (single memset 32K..40K)
    //  44K   ovs 32 KB | 76K ovd 32 KB | 108K ovw 32 KB
    //  512K  deg 400 KB | 1M dinv 400 KB | 2M part 19.2 MB | 22M agg 25.6 MB
    char* wsb = (char*)d_ws;
    float* W       = (float*)(wsb);
    float* MT      = (float*)(wsb + (16u << 10));
    int*   gcnt    = (int*)  (wsb + (32u << 10));
    int*   ovf_cnt = (int*)  (wsb + (39u << 10));
    int*   ticket  = (int*)  (wsb + (39u << 10) + 64u);
    int*   ovs     = (int*)  (wsb + (44u << 10));
    int*   ovd     = (int*)  (wsb + (76u << 10));
    float* ovw     = (float*)(wsb + (108u << 10));
    float* deg     = (float*)(wsb + (512u << 10));
    float* dinv    = (float*)(wsb + (1u << 20));
    int2*  part    = (int2*) (wsb + (2u << 20));
    float* agg     = (float*)(wsb + (22u << 20));

    hipMemsetAsync(gcnt, 0, (8u << 10), stream);   // zeroes gcnt + ovf_cnt + ticket

    k_evolve<<<64, 64, 0, stream>>>(W0, gWi, gWh, gbi, gbh, W);
    k_matM<<<64, 64, 0, stream>>>(W, pW, MT);
    k_part<<<(E + PSTAGE - 1) / PSTAGE, 1024, 0, stream>>>(src, dst, ew, gcnt, part,
                                                           ovf_cnt, ovs, ovd, ovw, E);
    k_deg2<<<NBINS, 256, 0, stream>>>(gcnt, part, ovf_cnt, ovd, ovw, deg, dinv, N);
    k_gather2<<<GGRID, 256, 0, stream>>>(x, dinv, gcnt, part, agg, ticket,
                                         ovf_cnt, ovs, ovd, ovw, N);
    k_head<<<NBINS, 256, 0, stream>>>(agg, MT, pb, lW, lb, x, dinv,
                                      ovf_cnt, ovs, ovd, ovw, out, N);
}

// Round 18
// 225.222 us; speedup vs baseline: 1.1981x; 1.1981x over previous
//
#include <hip/hip_runtime.h>
#include <stdint.h>

#define FDIM 64
#define BINSH 6
#define NBINS 1563         // ceil(100000 / 64)
#define BCAP 1536          // bin capacity; mean 1024, sigma ~32 -> 16 sigma margin
#define OVCAP 8192         // overflow-edge capacity (expected usage: 0)
#define PSTAGE 4096        // edges staged per k_part block

// ---------- sentinel ----------
__global__ __launch_bounds__(256) void k_sentinel(float* out, int N, float val) {
    int n = blockIdx.x * 256 + threadIdx.x;
    if (n < N) out[n] = (n == 0) ? val : 0.f;
}

// ---------- 1. GRU weight evolution: W = (1-z)*n + z*W0 ----------
__global__ __launch_bounds__(64) void k_evolve(
    const float* __restrict__ W0, const float* __restrict__ Wi,
    const float* __restrict__ Wh, const float* __restrict__ bi,
    const float* __restrict__ bh, float* __restrict__ W) {
    int i = blockIdx.x;
    int j = threadIdx.x;
    __shared__ float w0s[64];
    w0s[j] = W0[i * 64 + j];
    __syncthreads();
    float a0 = 0.f, a1 = 0.f, a2 = 0.f, b0 = 0.f, b1 = 0.f, b2 = 0.f;
#pragma unroll 8
    for (int k = 0; k < 64; k++) {
        float w0k = w0s[k];
        a0 += w0k * Wi[(j)       * 64 + k];
        a1 += w0k * Wi[(64 + j)  * 64 + k];
        a2 += w0k * Wi[(128 + j) * 64 + k];
        b0 += w0k * Wh[(j)       * 64 + k];
        b1 += w0k * Wh[(64 + j)  * 64 + k];
        b2 += w0k * Wh[(128 + j) * 64 + k];
    }
    float ir = a0 + bi[j],        hr = b0 + bh[j];
    float iz = a1 + bi[64 + j],   hz = b1 + bh[64 + j];
    float in_ = a2 + bi[128 + j], hn = b2 + bh[128 + j];
    float r = 1.f / (1.f + expf(-(ir + hr)));
    float z = 1.f / (1.f + expf(-(iz + hz)));
    float n = tanhf(in_ + r * hn);
    W[i * 64 + j] = (1.f - z) * n + z * w0s[j];
}

// ---------- 2. MT[j][k] = (W @ projW^T)[k][j] ----------
__global__ __launch_bounds__(64) void k_matM(
    const float* __restrict__ W, const float* __restrict__ projW,
    float* __restrict__ MT) {
    int k = blockIdx.x;
    int j = threadIdx.x;
    __shared__ float wr[64];
    wr[j] = W[k * 64 + j];
    __syncthreads();
    float s = 0.f;
#pragma unroll 8
    for (int q = 0; q < 64; q++) s += wr[q] * projW[j * 64 + q];
    MT[j * 64 + k] = s;
}

// ---------- 3. partition: LDS counting sort by bin -> contiguous run writes ----------
__global__ __launch_bounds__(1024) void k_part(
    const int* __restrict__ src, const int* __restrict__ dst,
    const float* __restrict__ ew, int* __restrict__ gcnt,
    int2* __restrict__ part, int* __restrict__ ovf_cnt,
    int* __restrict__ ovs, int* __restrict__ ovd, float* __restrict__ ovw,
    int E) {
    __shared__ int  hist[NBINS];
    __shared__ int  scn[NBINS];
    __shared__ int  lcur[NBINS];
    __shared__ int2 stage[PSTAGE];
    __shared__ unsigned short sbin[PSTAGE];
    int t = threadIdx.x;
    for (int b = t; b < NBINS; b += 1024) hist[b] = 0;
    __syncthreads();
    int e0 = blockIdx.x * PSTAGE;
    int cnt = E - e0; if (cnt > PSTAGE) cnt = PSTAGE;
    for (int i = t; i < cnt; i += 1024) atomicAdd(&hist[dst[e0 + i] >> BINSH], 1);
    __syncthreads();
    for (int b = t; b < NBINS; b += 1024) scn[b] = hist[b];
    __syncthreads();
    for (int off = 1; off < NBINS; off <<= 1) {
        int i1 = t, i2 = t + 1024;
        int a1 = (i1 < NBINS && i1 >= off) ? scn[i1 - off] : 0;
        int a2 = (i2 < NBINS && i2 >= off) ? scn[i2 - off] : 0;
        __syncthreads();
        if (i1 < NBINS) scn[i1] += a1;
        if (i2 < NBINS) scn[i2] += a2;
        __syncthreads();
    }
    for (int b = t; b < NBINS; b += 1024) {
        int h = hist[b];
        int lbase = scn[b] - h;
        int gb = h ? atomicAdd(&gcnt[b], h) : 0;
        lcur[b] = lbase;
        hist[b] = gb - lbase;
    }
    __syncthreads();
    for (int i = t; i < cnt; i += 1024) {
        int e = e0 + i;
        int d = dst[e];
        int b = d >> BINSH;
        int p = atomicAdd(&lcur[b], 1);
        stage[p] = make_int2(src[e] | ((d & 63) << 20), __float_as_int(ew[e]));
        sbin[p] = (unsigned short)b;
    }
    __syncthreads();
    for (int i = t; i < cnt; i += 1024) {
        int b = sbin[i];
        int2 e = stage[i];
        int p = i + hist[b];
        if (p < BCAP) {
            part[(size_t)b * BCAP + p] = e;
        } else {
            int op = atomicAdd(ovf_cnt, 1);
            if (op < OVCAP) {
                ovs[op] = e.x & 0xFFFFF;
                ovd[op] = (b << BINSH) | ((e.x >> 20) & 63);
                ovw[op] = __int_as_float(e.y);
            }
        }
    }
}

// ---------- 4. deg + dinv per bin; ovf entries folded in (normally none) ----------
__global__ __launch_bounds__(256) void k_deg2(
    const int* __restrict__ gcnt, const int2* __restrict__ part,
    const int* __restrict__ ovf_cnt, const int* __restrict__ ovd,
    const float* __restrict__ ovw,
    float* __restrict__ deg, float* __restrict__ dinv, int N) {
    __shared__ float dl[64];
    int t = threadIdx.x, b = blockIdx.x;
    if (t < 64) dl[t] = 1.0f;   // self-loop
    __syncthreads();
    int c = gcnt[b]; if (c > BCAP) c = BCAP;
    const int2* pe = part + (size_t)b * BCAP;
    for (int i = t; i < c; i += 256) {
        int2 e = pe[i];
        atomicAdd(&dl[(e.x >> 20) & 63], __int_as_float(e.y));
    }
    int m = *ovf_cnt; if (m > OVCAP) m = OVCAP;   // normally 0
    for (int i = t; i < m; i += 256) {
        int d = ovd[i];
        if ((d >> BINSH) == b) atomicAdd(&dl[d & 63], ovw[i]);
    }
    __syncthreads();
    int n = b * 64 + t;
    if (t < 64 && n < N) {
        float d = dl[t];
        deg[n] = d;
        dinv[n] = d > 0.f ? rsqrtf(d) : 0.f;
    }
}

// ---------- 5. gather: 64-node bins; dinv folded into ledge; 2-way unrolled ----------
__global__ __launch_bounds__(256) void k_gather2(
    const float* __restrict__ x, const float* __restrict__ dinv,
    const int* __restrict__ gcnt, const int2* __restrict__ part,
    float* __restrict__ agg, int N) {
    __shared__ int  lcnt[64];
    __shared__ int  loff[65];
    __shared__ int  lcur[64];
    __shared__ int2 ledge[BCAP];   // {src | nl<<20, dinv[src]*ew}
    int t = threadIdx.x, b = blockIdx.x;
    if (t < 64) lcnt[t] = 0;
    __syncthreads();
    int c = gcnt[b]; if (c > BCAP) c = BCAP;
    const int2* pe = part + (size_t)b * BCAP;
    for (int i = t; i < c; i += 256) {
        atomicAdd(&lcnt[(pe[i].x >> 20) & 63], 1);
    }
    __syncthreads();
    if (t == 0) {
        int o = 0;
#pragma unroll 16
        for (int k = 0; k < 64; k++) { loff[k] = o; o += lcnt[k]; }
        loff[64] = o;
    }
    __syncthreads();
    if (t < 64) lcur[t] = loff[t];
    __syncthreads();
    // reorder + pre-multiply dinv[src] (streaming phase: high MLP absorbs the
    // random dinv load, removing it from the latency-critical gather loop)
    for (int i = t; i < c; i += 256) {
        int2 e = pe[i];
        int s = e.x & 0xFFFFF;
        float nw = dinv[s] * __int_as_float(e.y);
        int p = atomicAdd(&lcur[(e.x >> 20) & 63], 1);
        ledge[p] = make_int2(e.x, __float_as_int(nw));
    }
    __syncthreads();
    int wv = t >> 6, lane = t & 63, eg = lane >> 4, f = (lane & 15) * 4;
    for (int nl = wv; nl < 64; nl += 4) {
        int n = b * 64 + nl;
        if (n >= N) continue;
        float dn = dinv[n];
        int beg = loff[nl], end = loff[nl + 1];
        float ax = 0.f, ay = 0.f, az = 0.f, aw = 0.f;
        float bx = 0.f, by = 0.f, bz = 0.f, bw = 0.f;
        int i = beg + eg;
        // 2-way unroll: two independent x-row loads in flight per thread
        for (; i + 4 < end; i += 8) {
            int2 e0 = ledge[i];
            int2 e1 = ledge[i + 4];
            int s0 = e0.x & 0xFFFFF, s1 = e1.x & 0xFFFFF;
            float4 v0 = *(const float4*)&x[(size_t)s0 * 64 + f];
            float4 v1 = *(const float4*)&x[(size_t)s1 * 64 + f];
            float nm0 = __int_as_float(e0.y);
            float nm1 = __int_as_float(e1.y);
            ax += nm0 * v0.x; ay += nm0 * v0.y; az += nm0 * v0.z; aw += nm0 * v0.w;
            bx += nm1 * v1.x; by += nm1 * v1.y; bz += nm1 * v1.z; bw += nm1 * v1.w;
        }
        for (; i < end; i += 4) {
            int2 e = ledge[i];
            int s = e.x & 0xFFFFF;
            float nm = __int_as_float(e.y);
            float4 xv = *(const float4*)&x[(size_t)s * 64 + f];
            ax += nm * xv.x; ay += nm * xv.y; az += nm * xv.z; aw += nm * xv.w;
        }
        ax += bx; ay += by; az += bz; aw += bw;
        ax *= dn; ay *= dn; az *= dn; aw *= dn;
        ax += __shfl_xor(ax, 16); ay += __shfl_xor(ay, 16);
        az += __shfl_xor(az, 16); aw += __shfl_xor(aw, 16);
        ax += __shfl_xor(ax, 32); ay += __shfl_xor(ay, 32);
        az += __shfl_xor(az, 32); aw += __shfl_xor(aw, 32);
        if (eg == 0) {
            float sl = dn * dn;
            float4 xv = *(const float4*)&x[(size_t)n * 64 + f];  // self-loop
            float4 o = make_float4(ax + sl * xv.x, ay + sl * xv.y,
                                   az + sl * xv.z, aw + sl * xv.w);
            *(float4*)&agg[(size_t)n * 64 + f] = o;
        }
    }
}

// ---------- 6. head: out = relu(agg @ M + pb) @ linW^T + lb ; ovf patched in ----------
__global__ __launch_bounds__(256) void k_head(
    const float* __restrict__ agg, const float* __restrict__ MT,
    const float* __restrict__ projB, const float* __restrict__ linW,
    const float* __restrict__ linB, const float* __restrict__ x,
    const float* __restrict__ dinv, const int* __restrict__ ovf_cnt,
    const int* __restrict__ ovs, const int* __restrict__ ovd,
    const float* __restrict__ ovw, float* __restrict__ out, int N) {
    __shared__ float hs[64 * 68];
    __shared__ float ps[64 * 68];
    __shared__ float red[64 * 17];
    __shared__ float pbs[64], lws[64];
    int t  = threadIdx.x;
    int nb = blockIdx.x * 64;
#pragma unroll
    for (int i = 0; i < 4; i++) {
        int lin = i * 1024 + t * 4;
        int row = lin >> 6, col = lin & 63;
        int node = nb + row;
        float4 v = make_float4(0.f, 0.f, 0.f, 0.f);
        if (node < N) v = *(const float4*)(agg + (size_t)node * 64 + col);
        *(float4*)&hs[row * 68 + col] = v;
        *(float4*)&ps[row * 68 + col] = *(const float4*)(MT + lin);
    }
    if (t < 64) { pbs[t] = projB[t]; lws[t] = linW[t]; }
    __syncthreads();
    // ovf patch for this 64-node tile (normally m==0 -> one scalar read)
    int m = *ovf_cnt; if (m > OVCAP) m = OVCAP;
    for (int i = t; i < m; i += 256) {
        int d = ovd[i];
        if ((d >> BINSH) == blockIdx.x && d < N) {
            int s = ovs[i];
            float nm = dinv[s] * ovw[i] * dinv[d];
            int nl = d & 63;
            for (int ff = 0; ff < 64; ff++)
                atomicAdd(&hs[nl * 68 + ff], nm * x[(size_t)s * 64 + ff]);
        }
    }
    if (m) __syncthreads();
    int tj = t & 15, tn = t >> 4;
    float acc[4][4] = {};
    for (int k = 0; k < 64; k += 4) {
        float4 hv[4], pv[4];
#pragma unroll
        for (int nn = 0; nn < 4; nn++) hv[nn] = *(const float4*)&hs[(tn * 4 + nn) * 68 + k];
#pragma unroll
        for (int jj = 0; jj < 4; jj++) pv[jj] = *(const float4*)&ps[(tj * 4 + jj) * 68 + k];
#pragma unroll
        for (int nn = 0; nn < 4; nn++) {
            const float* hp = (const float*)&hv[nn];
#pragma unroll
            for (int jj = 0; jj < 4; jj++) {
                const float* pp = (const float*)&pv[jj];
                acc[nn][jj] += hp[0] * pp[0] + hp[1] * pp[1] + hp[2] * pp[2] + hp[3] * pp[3];
            }
        }
    }
    float lb = linB[0];
#pragma unroll
    for (int nn = 0; nn < 4; nn++) {
        float s = 0.f;
#pragma unroll
        for (int jj = 0; jj < 4; jj++) {
            int j = tj * 4 + jj;
            float v = acc[nn][jj] + pbs[j];
            v = v > 0.f ? v : 0.f;
            s += v * lws[j];
        }
        red[(tn * 4 + nn) * 17 + tj] = s;
    }
    __syncthreads();
    if (t < 64) {
        float s = lb;
#pragma unroll
        for (int q = 0; q < 16; q++) s += red[t * 17 + q];
        int node = nb + t;
        if (node < N) out[node] = s;
    }
}

extern "C" void kernel_launch(void* const* d_in, const int* in_sizes, int n_in,
                              void* d_out, int out_size, void* d_ws, size_t ws_size,
                              hipStream_t stream) {
    const float* x   = (const float*)d_in[0];
    const int*   ei  = (const int*)d_in[1];
    const float* ew  = (const float*)d_in[2];
    const float* W0  = (const float*)d_in[3];
    const float* gWi = (const float*)d_in[4];
    const float* gWh = (const float*)d_in[5];
    const float* gbi = (const float*)d_in[6];
    const float* gbh = (const float*)d_in[7];
    const float* pW  = (const float*)d_in[8];
    const float* pb  = (const float*)d_in[9];
    const float* lW  = (const float*)d_in[10];
    const float* lb  = (const float*)d_in[11];
    float* out = (float*)d_out;

    static const int EXPSZ[12] = {6400000, 3200000, 1600000, 4096, 12288, 12288,
                                  192, 192, 4096, 64, 64, 1};
    int mism = -1;
    for (int i = 0; i < 12 && i < n_in; i++)
        if (in_sizes[i] != EXPSZ[i]) { mism = i; break; }
    if (mism >= 0) {
        k_sentinel<<<(out_size + 255) / 256, 256, 0, stream>>>(out, out_size,
                                                               ldexpf(1.f, 30 + 3 * mism));
        return;
    }

    int N = in_sizes[0] / FDIM;          // 100000
    int E = in_sizes[1] / 2;             // 1600000
    const int* src = ei;
    const int* dst = ei + E;

    // ws layout (bytes):
    //  0     W 16 KB | 16K MT 16 KB
    //  32K   gcnt 6.3 KB | 39K ovf_cnt 4 B       (single memset 32K..40K)
    //  44K   ovs 32 KB | 76K ovd 32 KB | 108K ovw 32 KB
    //  512K  deg 400 KB | 1M dinv 400 KB | 2M part 19.2 MB | 22M agg 25.6 MB
    char* wsb = (char*)d_ws;
    float* W       = (float*)(wsb);
    float* MT      = (float*)(wsb + (16u << 10));
    int*   gcnt    = (int*)  (wsb + (32u << 10));
    int*   ovf_cnt = (int*)  (wsb + (39u << 10));
    int*   ovs     = (int*)  (wsb + (44u << 10));
    int*   ovd     = (int*)  (wsb + (76u << 10));
    float* ovw     = (float*)(wsb + (108u << 10));
    float* deg     = (float*)(wsb + (512u << 10));
    float* dinv    = (float*)(wsb + (1u << 20));
    int2*  part    = (int2*) (wsb + (2u << 20));
    float* agg     = (float*)(wsb + (22u << 20));

    hipMemsetAsync(gcnt, 0, (8u << 10), stream);   // zeroes gcnt + ovf_cnt

    k_evolve<<<64, 64, 0, stream>>>(W0, gWi, gWh, gbi, gbh, W);
    k_matM<<<64, 64, 0, stream>>>(W, pW, MT);
    k_part<<<(E + PSTAGE - 1) / PSTAGE, 1024, 0, stream>>>(src, dst, ew, gcnt, part,
                                                           ovf_cnt, ovs, ovd, ovw, E);
    k_deg2<<<NBINS, 256, 0, stream>>>(gcnt, part, ovf_cnt, ovd, ovw, deg, dinv, N);
    k_gather2<<<NBINS, 256, 0, stream>>>(x, dinv, gcnt, part, agg, N);
    k_head<<<NBINS, 256, 0, stream>>>(agg, MT, pb, lW, lb, x, dinv,
                                      ovf_cnt, ovs, ovd, ovw, out, N);
}

// Round 20
// 206.563 us; speedup vs baseline: 1.3063x; 1.0903x over previous
//
#include <hip/hip_runtime.h>
#include <stdint.h>

#define FDIM 64
#define BINSH 6
#define NBINS 1563         // ceil(100000 / 64)
#define BCAP 1536          // bin capacity; mean 1024, sigma ~32 -> 16 sigma margin
#define OVCAP 8192         // overflow-edge capacity (expected usage: 0)
#define PSTAGE 4096        // edges staged per k_part block

__device__ __forceinline__ float bf2f(unsigned int u) {
    union { float f; uint32_t i; } v; v.i = (u & 0xFFFFu) << 16; return v.f;
}
__device__ __forceinline__ unsigned short f2bf(float f) {
    union { float f; uint32_t i; } v; v.f = f;
    uint32_t u = v.i;
    u += 0x7FFFu + ((u >> 16) & 1u);   // RNE
    return (unsigned short)(u >> 16);
}

// ---------- sentinel ----------
__global__ __launch_bounds__(256) void k_sentinel(float* out, int N, float val) {
    int n = blockIdx.x * 256 + threadIdx.x;
    if (n < N) out[n] = (n == 0) ? val : 0.f;
}

// ---------- 1. GRU weight evolution: W = (1-z)*n + z*W0 ----------
__global__ __launch_bounds__(64) void k_evolve(
    const float* __restrict__ W0, const float* __restrict__ Wi,
    const float* __restrict__ Wh, const float* __restrict__ bi,
    const float* __restrict__ bh, float* __restrict__ W) {
    int i = blockIdx.x;
    int j = threadIdx.x;
    __shared__ float w0s[64];
    w0s[j] = W0[i * 64 + j];
    __syncthreads();
    float a0 = 0.f, a1 = 0.f, a2 = 0.f, b0 = 0.f, b1 = 0.f, b2 = 0.f;
#pragma unroll 8
    for (int k = 0; k < 64; k++) {
        float w0k = w0s[k];
        a0 += w0k * Wi[(j)       * 64 + k];
        a1 += w0k * Wi[(64 + j)  * 64 + k];
        a2 += w0k * Wi[(128 + j) * 64 + k];
        b0 += w0k * Wh[(j)       * 64 + k];
        b1 += w0k * Wh[(64 + j)  * 64 + k];
        b2 += w0k * Wh[(128 + j) * 64 + k];
    }
    float ir = a0 + bi[j],        hr = b0 + bh[j];
    float iz = a1 + bi[64 + j],   hz = b1 + bh[64 + j];
    float in_ = a2 + bi[128 + j], hn = b2 + bh[128 + j];
    float r = 1.f / (1.f + expf(-(ir + hr)));
    float z = 1.f / (1.f + expf(-(iz + hz)));
    float n = tanhf(in_ + r * hn);
    W[i * 64 + j] = (1.f - z) * n + z * w0s[j];
}

// ---------- 2. M[k][j] = sum_q W[k,q]*projW[j,q]   (M = W @ projW^T) ----------
__global__ __launch_bounds__(64) void k_matM(
    const float* __restrict__ W, const float* __restrict__ projW,
    float* __restrict__ M) {
    int k = blockIdx.x;
    int j = threadIdx.x;
    __shared__ float wr[64];
    wr[j] = W[k * 64 + j];
    __syncthreads();
    float s = 0.f;
#pragma unroll 8
    for (int q = 0; q < 64; q++) s += wr[q] * projW[j * 64 + q];
    M[k * 64 + j] = s;
}

// ---------- 3. xm = bf16(x @ M)  — folds W and projW into one gather operand ----------
__global__ __launch_bounds__(256) void k_xm(
    const float* __restrict__ x, const float* __restrict__ M,
    unsigned short* __restrict__ xm, int N) {
    __shared__ float xs[64 * 68];
    __shared__ float ms[64 * 68];
    int t  = threadIdx.x;
    int nb = blockIdx.x * 64;
#pragma unroll
    for (int i = 0; i < 4; i++) {
        int lin = i * 1024 + t * 4;
        int row = lin >> 6, col = lin & 63;
        int node = nb + row;
        float4 v = make_float4(0.f, 0.f, 0.f, 0.f);
        if (node < N) v = *(const float4*)(x + (size_t)node * 64 + col);
        *(float4*)&xs[row * 68 + col] = v;
        *(float4*)&ms[row * 68 + col] = *(const float4*)(M + lin);
    }
    __syncthreads();
    int tj = t & 15, tn = t >> 4;
    float acc[4][4] = {};
    for (int k = 0; k < 64; k += 4) {
        float4 xv[4], mv[4];
#pragma unroll
        for (int nn = 0; nn < 4; nn++) xv[nn] = *(const float4*)&xs[(tn * 4 + nn) * 68 + k];
#pragma unroll
        for (int kk = 0; kk < 4; kk++) mv[kk] = *(const float4*)&ms[(k + kk) * 68 + tj * 4];
#pragma unroll
        for (int nn = 0; nn < 4; nn++) {
            const float* xp = (const float*)&xv[nn];
#pragma unroll
            for (int kk = 0; kk < 4; kk++) {
                float xk = xp[kk];
                const float* mp = (const float*)&mv[kk];
                acc[nn][0] += xk * mp[0];
                acc[nn][1] += xk * mp[1];
                acc[nn][2] += xk * mp[2];
                acc[nn][3] += xk * mp[3];
            }
        }
    }
#pragma unroll
    for (int nn = 0; nn < 4; nn++) {
        int node = nb + tn * 4 + nn;
        if (node < N) {
            ushort4 o;
            o.x = f2bf(acc[nn][0]); o.y = f2bf(acc[nn][1]);
            o.z = f2bf(acc[nn][2]); o.w = f2bf(acc[nn][3]);
            *(ushort4*)&xm[(size_t)node * 64 + tj * 4] = o;
        }
    }
}

// ---------- 4. partition: LDS counting sort by bin -> contiguous run writes ----------
__global__ __launch_bounds__(1024) void k_part(
    const int* __restrict__ src, const int* __restrict__ dst,
    const float* __restrict__ ew, int* __restrict__ gcnt,
    int2* __restrict__ part, int* __restrict__ ovf_cnt,
    int* __restrict__ ovs, int* __restrict__ ovd, float* __restrict__ ovw,
    int E) {
    __shared__ int  hist[NBINS];
    __shared__ int  scn[NBINS];
    __shared__ int  lcur[NBINS];
    __shared__ int2 stage[PSTAGE];
    __shared__ unsigned short sbin[PSTAGE];
    int t = threadIdx.x;
    for (int b = t; b < NBINS; b += 1024) hist[b] = 0;
    __syncthreads();
    int e0 = blockIdx.x * PSTAGE;
    int cnt = E - e0; if (cnt > PSTAGE) cnt = PSTAGE;
    for (int i = t; i < cnt; i += 1024) atomicAdd(&hist[dst[e0 + i] >> BINSH], 1);
    __syncthreads();
    for (int b = t; b < NBINS; b += 1024) scn[b] = hist[b];
    __syncthreads();
    for (int off = 1; off < NBINS; off <<= 1) {
        int i1 = t, i2 = t + 1024;
        int a1 = (i1 < NBINS && i1 >= off) ? scn[i1 - off] : 0;
        int a2 = (i2 < NBINS && i2 >= off) ? scn[i2 - off] : 0;
        __syncthreads();
        if (i1 < NBINS) scn[i1] += a1;
        if (i2 < NBINS) scn[i2] += a2;
        __syncthreads();
    }
    for (int b = t; b < NBINS; b += 1024) {
        int h = hist[b];
        int lbase = scn[b] - h;
        int gb = h ? atomicAdd(&gcnt[b], h) : 0;
        lcur[b] = lbase;
        hist[b] = gb - lbase;
    }
    __syncthreads();
    for (int i = t; i < cnt; i += 1024) {
        int e = e0 + i;
        int d = dst[e];
        int b = d >> BINSH;
        int p = atomicAdd(&lcur[b], 1);
        stage[p] = make_int2(src[e] | ((d & 63) << 20), __float_as_int(ew[e]));
        sbin[p] = (unsigned short)b;
    }
    __syncthreads();
    for (int i = t; i < cnt; i += 1024) {
        int b = sbin[i];
        int2 e = stage[i];
        int p = i + hist[b];
        if (p < BCAP) {
            part[(size_t)b * BCAP + p] = e;
        } else {
            int op = atomicAdd(ovf_cnt, 1);
            if (op < OVCAP) {
                ovs[op] = e.x & 0xFFFFF;
                ovd[op] = (b << BINSH) | ((e.x >> 20) & 63);
                ovw[op] = __int_as_float(e.y);
            }
        }
    }
}

// ---------- 5. deg + dinv per bin; ovf entries folded in (normally none) ----------
__global__ __launch_bounds__(256) void k_deg2(
    const int* __restrict__ gcnt, const int2* __restrict__ part,
    const int* __restrict__ ovf_cnt, const int* __restrict__ ovd,
    const float* __restrict__ ovw,
    float* __restrict__ deg, float* __restrict__ dinv, int N) {
    __shared__ float dl[64];
    int t = threadIdx.x, b = blockIdx.x;
    if (t < 64) dl[t] = 1.0f;   // self-loop
    __syncthreads();
    int c = gcnt[b]; if (c > BCAP) c = BCAP;
    const int2* pe = part + (size_t)b * BCAP;
    for (int i = t; i < c; i += 256) {
        int2 e = pe[i];
        atomicAdd(&dl[(e.x >> 20) & 63], __int_as_float(e.y));
    }
    int m = *ovf_cnt; if (m > OVCAP) m = OVCAP;   // normally 0
    for (int i = t; i < m; i += 256) {
        int d = ovd[i];
        if ((d >> BINSH) == b) atomicAdd(&dl[d & 63], ovw[i]);
    }
    __syncthreads();
    int n = b * 64 + t;
    if (t < 64 && n < N) {
        float d = dl[t];
        deg[n] = d;
        dinv[n] = d > 0.f ? rsqrtf(d) : 0.f;
    }
}

// ---------- 6. FUSED gather(bf16 xm) + head epilogue: out in one pass ----------
__global__ __launch_bounds__(256) void k_gf(
    const unsigned short* __restrict__ xm, const float* __restrict__ dinv,
    const int* __restrict__ gcnt, const int2* __restrict__ part,
    const float* __restrict__ projB, const float* __restrict__ linW,
    const float* __restrict__ linB, const int* __restrict__ ovf_cnt,
    const int* __restrict__ ovs, const int* __restrict__ ovd,
    const float* __restrict__ ovw, float* __restrict__ out, int N) {
    __shared__ int  lcnt[64];
    __shared__ int  loff[65];
    __shared__ int  lcur[64];
    __shared__ int2 ledge[BCAP];   // {src | nl<<20, dinv[src]*ew}
    __shared__ float pbs[64], lws[64];
    int t = threadIdx.x, b = blockIdx.x;
    if (t < 64) { lcnt[t] = 0; pbs[t] = projB[t]; lws[t] = linW[t]; }
    __syncthreads();
    int c = gcnt[b]; if (c > BCAP) c = BCAP;
    const int2* pe = part + (size_t)b * BCAP;
    for (int i = t; i < c; i += 256) {
        atomicAdd(&lcnt[(pe[i].x >> 20) & 63], 1);
    }
    __syncthreads();
    if (t == 0) {
        int o = 0;
#pragma unroll 16
        for (int k = 0; k < 64; k++) { loff[k] = o; o += lcnt[k]; }
        loff[64] = o;
    }
    __syncthreads();
    if (t < 64) lcur[t] = loff[t];
    __syncthreads();
    // reorder + premultiply dinv[src] (streaming phase absorbs the random dinv read)
    for (int i = t; i < c; i += 256) {
        int2 e = pe[i];
        int s = e.x & 0xFFFFF;
        float nw = dinv[s] * __int_as_float(e.y);
        int p = atomicAdd(&lcur[(e.x >> 20) & 63], 1);
        ledge[p] = make_int2(e.x, __float_as_int(nw));
    }
    __syncthreads();
    int m = *ovf_cnt; if (m > OVCAP) m = OVCAP;   // normally 0
    float lb = linB[0];
    int wv = t >> 6, lane = t & 63, eg = lane >> 4, fq = lane & 15, f = fq * 4;
    for (int nl = wv; nl < 64; nl += 4) {
        int n = b * 64 + nl;
        if (n >= N) continue;
        float dn = dinv[n];
        int beg = loff[nl], end = loff[nl + 1];
        float ax = 0.f, ay = 0.f, az = 0.f, aw = 0.f;
        float bx = 0.f, by = 0.f, bz = 0.f, bw = 0.f;
        int i = beg + eg;
        for (; i + 4 < end; i += 8) {      // 2 independent bf16 row loads in flight
            int2 e0 = ledge[i];
            int2 e1 = ledge[i + 4];
            int s0 = e0.x & 0xFFFFF, s1 = e1.x & 0xFFFFF;
            uint2 u0 = *(const uint2*)&xm[(size_t)s0 * 64 + f];
            uint2 u1 = *(const uint2*)&xm[(size_t)s1 * 64 + f];
            float nm0 = __int_as_float(e0.y);
            float nm1 = __int_as_float(e1.y);
            ax += nm0 * bf2f(u0.x);       ay += nm0 * bf2f(u0.x >> 16);
            az += nm0 * bf2f(u0.y);       aw += nm0 * bf2f(u0.y >> 16);
            bx += nm1 * bf2f(u1.x);       by += nm1 * bf2f(u1.x >> 16);
            bz += nm1 * bf2f(u1.y);       bw += nm1 * bf2f(u1.y >> 16);
        }
        for (; i < end; i += 4) {
            int2 e = ledge[i];
            int s = e.x & 0xFFFFF;
            float nm = __int_as_float(e.y);
            uint2 u = *(const uint2*)&xm[(size_t)s * 64 + f];
            ax += nm * bf2f(u.x); ay += nm * bf2f(u.x >> 16);
            az += nm * bf2f(u.y); aw += nm * bf2f(u.y >> 16);
        }
        ax += bx; ay += by; az += bz; aw += bw;
        ax *= dn; ay *= dn; az *= dn; aw *= dn;
        // reduce the 4 edge-groups FIRST (bug in R19: self-loop was added
        // before this reduction in all 4 groups -> counted 4x)
        ax += __shfl_xor(ax, 16); ay += __shfl_xor(ay, 16);
        az += __shfl_xor(az, 16); aw += __shfl_xor(aw, 16);
        ax += __shfl_xor(ax, 32); ay += __shfl_xor(ay, 32);
        az += __shfl_xor(az, 32); aw += __shfl_xor(aw, 32);
        if (eg == 0) {
            // self-loop (exactly once, post-reduction)
            {
                uint2 u = *(const uint2*)&xm[(size_t)n * 64 + f];
                float sl = dn * dn;
                ax += sl * bf2f(u.x); ay += sl * bf2f(u.x >> 16);
                az += sl * bf2f(u.y); aw += sl * bf2f(u.y >> 16);
            }
            // ovf patch for this node (normally m==0)
            for (int q = 0; q < m; q++) {
                if (ovd[q] == n) {
                    int s = ovs[q];
                    float nm = dinv[s] * ovw[q] * dn;
                    uint2 u = *(const uint2*)&xm[(size_t)s * 64 + f];
                    ax += nm * bf2f(u.x); ay += nm * bf2f(u.x >> 16);
                    az += nm * bf2f(u.y); aw += nm * bf2f(u.y >> 16);
                }
            }
            // head epilogue: s = sum_f relu(aggm[f]+pb[f])*lW[f]
            float v0 = ax + pbs[f],     v1 = ay + pbs[f + 1];
            float v2 = az + pbs[f + 2], v3 = aw + pbs[f + 3];
            float s = (v0 > 0.f ? v0 : 0.f) * lws[f]
                    + (v1 > 0.f ? v1 : 0.f) * lws[f + 1]
                    + (v2 > 0.f ? v2 : 0.f) * lws[f + 2]
                    + (v3 > 0.f ? v3 : 0.f) * lws[f + 3];
            s += __shfl_xor(s, 1); s += __shfl_xor(s, 2);
            s += __shfl_xor(s, 4); s += __shfl_xor(s, 8);
            if (fq == 0) out[n] = s + lb;
        }
    }
}

extern "C" void kernel_launch(void* const* d_in, const int* in_sizes, int n_in,
                              void* d_out, int out_size, void* d_ws, size_t ws_size,
                              hipStream_t stream) {
    const float* x   = (const float*)d_in[0];
    const int*   ei  = (const int*)d_in[1];
    const float* ew  = (const float*)d_in[2];
    const float* W0  = (const float*)d_in[3];
    const float* gWi = (const float*)d_in[4];
    const float* gWh = (const float*)d_in[5];
    const float* gbi = (const float*)d_in[6];
    const float* gbh = (const float*)d_in[7];
    const float* pW  = (const float*)d_in[8];
    const float* pb  = (const float*)d_in[9];
    const float* lW  = (const float*)d_in[10];
    const float* lb  = (const float*)d_in[11];
    float* out = (float*)d_out;

    static const int EXPSZ[12] = {6400000, 3200000, 1600000, 4096, 12288, 12288,
                                  192, 192, 4096, 64, 64, 1};
    int mism = -1;
    for (int i = 0; i < 12 && i < n_in; i++)
        if (in_sizes[i] != EXPSZ[i]) { mism = i; break; }
    if (mism >= 0) {
        k_sentinel<<<(out_size + 255) / 256, 256, 0, stream>>>(out, out_size,
                                                               ldexpf(1.f, 30 + 3 * mism));
        return;
    }

    int N = in_sizes[0] / FDIM;          // 100000
    int E = in_sizes[1] / 2;             // 1600000
    const int* src = ei;
    const int* dst = ei + E;

    // ws layout (bytes):
    //  0     W 16 KB | 16K M 16 KB
    //  32K   gcnt 6.3 KB | 39K ovf_cnt 4 B       (single memset 32K..40K)
    //  44K   ovs 32 KB | 76K ovd 32 KB | 108K ovw 32 KB
    //  512K  deg 400 KB | 1M dinv 400 KB | 2M part 19.2 MB | 22M xm 12.8 MB
    char* wsb = (char*)d_ws;
    float* W       = (float*)(wsb);
    float* M       = (float*)(wsb + (16u << 10));
    int*   gcnt    = (int*)  (wsb + (32u << 10));
    int*   ovf_cnt = (int*)  (wsb + (39u << 10));
    int*   ovs     = (int*)  (wsb + (44u << 10));
    int*   ovd     = (int*)  (wsb + (76u << 10));
    float* ovw     = (float*)(wsb + (108u << 10));
    float* deg     = (float*)(wsb + (512u << 10));
    float* dinv    = (float*)(wsb + (1u << 20));
    int2*  part    = (int2*) (wsb + (2u << 20));
    unsigned short* xm = (unsigned short*)(wsb + (22u << 20));

    hipMemsetAsync(gcnt, 0, (8u << 10), stream);   // zeroes gcnt + ovf_cnt

    k_evolve<<<64, 64, 0, stream>>>(W0, gWi, gWh, gbi, gbh, W);
    k_matM<<<64, 64, 0, stream>>>(W, pW, M);
    k_xm<<<NBINS, 256, 0, stream>>>(x, M, xm, N);
    k_part<<<(E + PSTAGE - 1) / PSTAGE, 1024, 0, stream>>>(src, dst, ew, gcnt, part,
                                                           ovf_cnt, ovs, ovd, ovw, E);
    k_deg2<<<NBINS, 256, 0, stream>>>(gcnt, part, ovf_cnt, ovd, ovw, deg, dinv, N);
    k_gf<<<NBINS, 256, 0, stream>>>(xm, dinv, gcnt, part, pb, lW, lb,
                                    ovf_cnt, ovs, ovd, ovw, out, N);
}

// Round 21
// 195.914 us; speedup vs baseline: 1.3773x; 1.0544x over previous
//
#include <hip/hip_runtime.h>
#include <stdint.h>

#define FDIM 64
#define BINSH 6
#define NBINS 1563         // ceil(100000 / 64)
#define BCAP 1536          // bin capacity; mean 1024, sigma ~32 -> 16 sigma margin
#define OVCAP 8192         // overflow-edge capacity (expected usage: 0)
#define PSTAGE 8192        // edges per k_part block (sort removed -> LDS freed)

__device__ __forceinline__ float bf2f(unsigned int u) {
    union { float f; uint32_t i; } v; v.i = (u & 0xFFFFu) << 16; return v.f;
}
__device__ __forceinline__ unsigned short f2bf(float f) {
    union { float f; uint32_t i; } v; v.f = f;
    uint32_t u = v.i;
    u += 0x7FFFu + ((u >> 16) & 1u);   // RNE
    return (unsigned short)(u >> 16);
}

// ---------- sentinel ----------
__global__ __launch_bounds__(256) void k_sentinel(float* out, int N, float val) {
    int n = blockIdx.x * 256 + threadIdx.x;
    if (n < N) out[n] = (n == 0) ? val : 0.f;
}

// ---------- 1. FUSED: GRU evolve row i -> M row i ; also zeroes gcnt/ovf ----------
__global__ __launch_bounds__(64) void k_evolveM(
    const float* __restrict__ W0, const float* __restrict__ Wi,
    const float* __restrict__ Wh, const float* __restrict__ bi,
    const float* __restrict__ bh, const float* __restrict__ projW,
    float* __restrict__ M, int* __restrict__ gcnt, int* __restrict__ ovf_cnt) {
    int i = blockIdx.x;
    int j = threadIdx.x;
    // zero control vars (64 blocks x 64 threads = 4096 >= NBINS+1)
    int g = i * 64 + j;
    if (g < NBINS) gcnt[g] = 0;
    if (g == NBINS) *ovf_cnt = 0;
    __shared__ float w0s[64];
    __shared__ float wrow[64];
    w0s[j] = W0[i * 64 + j];
    __syncthreads();
    float a0 = 0.f, a1 = 0.f, a2 = 0.f, b0 = 0.f, b1 = 0.f, b2 = 0.f;
#pragma unroll 8
    for (int k = 0; k < 64; k++) {
        float w0k = w0s[k];
        a0 += w0k * Wi[(j)       * 64 + k];
        a1 += w0k * Wi[(64 + j)  * 64 + k];
        a2 += w0k * Wi[(128 + j) * 64 + k];
        b0 += w0k * Wh[(j)       * 64 + k];
        b1 += w0k * Wh[(64 + j)  * 64 + k];
        b2 += w0k * Wh[(128 + j) * 64 + k];
    }
    float ir = a0 + bi[j],        hr = b0 + bh[j];
    float iz = a1 + bi[64 + j],   hz = b1 + bh[64 + j];
    float in_ = a2 + bi[128 + j], hn = b2 + bh[128 + j];
    float r = 1.f / (1.f + expf(-(ir + hr)));
    float z = 1.f / (1.f + expf(-(iz + hz)));
    float n = tanhf(in_ + r * hn);
    wrow[j] = (1.f - z) * n + z * w0s[j];   // W[i][j], LDS only
    __syncthreads();
    // M[i][j] = sum_q W[i][q] * projW[j][q]
    float s = 0.f;
#pragma unroll 8
    for (int q = 0; q < 64; q++) s += wrow[q] * projW[j * 64 + q];
    M[i * 64 + j] = s;
}

// ---------- 2. xm = bf16(x @ M) ----------
__global__ __launch_bounds__(256) void k_xm(
    const float* __restrict__ x, const float* __restrict__ M,
    unsigned short* __restrict__ xm, int N) {
    __shared__ float xs[64 * 68];
    __shared__ float ms[64 * 68];
    int t  = threadIdx.x;
    int nb = blockIdx.x * 64;
#pragma unroll
    for (int i = 0; i < 4; i++) {
        int lin = i * 1024 + t * 4;
        int row = lin >> 6, col = lin & 63;
        int node = nb + row;
        float4 v = make_float4(0.f, 0.f, 0.f, 0.f);
        if (node < N) v = *(const float4*)(x + (size_t)node * 64 + col);
        *(float4*)&xs[row * 68 + col] = v;
        *(float4*)&ms[row * 68 + col] = *(const float4*)(M + lin);
    }
    __syncthreads();
    int tj = t & 15, tn = t >> 4;
    float acc[4][4] = {};
    for (int k = 0; k < 64; k += 4) {
        float4 xv[4], mv[4];
#pragma unroll
        for (int nn = 0; nn < 4; nn++) xv[nn] = *(const float4*)&xs[(tn * 4 + nn) * 68 + k];
#pragma unroll
        for (int kk = 0; kk < 4; kk++) mv[kk] = *(const float4*)&ms[(k + kk) * 68 + tj * 4];
#pragma unroll
        for (int nn = 0; nn < 4; nn++) {
            const float* xp = (const float*)&xv[nn];
#pragma unroll
            for (int kk = 0; kk < 4; kk++) {
                float xk = xp[kk];
                const float* mp = (const float*)&mv[kk];
                acc[nn][0] += xk * mp[0];
                acc[nn][1] += xk * mp[1];
                acc[nn][2] += xk * mp[2];
                acc[nn][3] += xk * mp[3];
            }
        }
    }
#pragma unroll
    for (int nn = 0; nn < 4; nn++) {
        int node = nb + tn * 4 + nn;
        if (node < N) {
            ushort4 o;
            o.x = f2bf(acc[nn][0]); o.y = f2bf(acc[nn][1]);
            o.z = f2bf(acc[nn][2]); o.w = f2bf(acc[nn][3]);
            *(ushort4*)&xm[(size_t)node * 64 + tj * 4] = o;
        }
    }
}

// ---------- 3. partition (no sort): LDS histogram -> block-run reservation ----------
__global__ __launch_bounds__(1024) void k_part(
    const int* __restrict__ src, const int* __restrict__ dst,
    const float* __restrict__ ew, int* __restrict__ gcnt,
    int2* __restrict__ part, int* __restrict__ ovf_cnt,
    int* __restrict__ ovs, int* __restrict__ ovd, float* __restrict__ ovw,
    int E) {
    __shared__ int hist[NBINS];
    __shared__ int lcur[NBINS];
    int t = threadIdx.x;
    for (int b = t; b < NBINS; b += 1024) hist[b] = 0;
    __syncthreads();
    int e0 = blockIdx.x * PSTAGE;
    int cnt = E - e0; if (cnt > PSTAGE) cnt = PSTAGE;
    for (int i = t; i < cnt; i += 1024) atomicAdd(&hist[dst[e0 + i] >> BINSH], 1);
    __syncthreads();
    // reserve a contiguous run per (block, bin); lcur starts at the global base
    for (int b = t; b < NBINS; b += 1024) {
        int h = hist[b];
        lcur[b] = h ? atomicAdd(&gcnt[b], h) : 0;
    }
    __syncthreads();
    for (int i = t; i < cnt; i += 1024) {
        int e = e0 + i;
        int d = dst[e];
        int b = d >> BINSH;
        int p = atomicAdd(&lcur[b], 1);    // global slot within this bin
        if (p < BCAP) {
            part[(size_t)b * BCAP + p] = make_int2(src[e] | ((d & 63) << 20),
                                                   __float_as_int(ew[e]));
        } else {
            int op = atomicAdd(ovf_cnt, 1);
            if (op < OVCAP) {
                ovs[op] = src[e];
                ovd[op] = d;
                ovw[op] = ew[e];
            }
        }
    }
}

// ---------- 4. deg + dinv per bin; ovf entries folded in (normally none) ----------
__global__ __launch_bounds__(256) void k_deg2(
    const int* __restrict__ gcnt, const int2* __restrict__ part,
    const int* __restrict__ ovf_cnt, const int* __restrict__ ovd,
    const float* __restrict__ ovw,
    float* __restrict__ deg, float* __restrict__ dinv, int N) {
    __shared__ float dl[64];
    int t = threadIdx.x, b = blockIdx.x;
    if (t < 64) dl[t] = 1.0f;   // self-loop
    __syncthreads();
    int c = gcnt[b]; if (c > BCAP) c = BCAP;
    const int2* pe = part + (size_t)b * BCAP;
    for (int i = t; i < c; i += 256) {
        int2 e = pe[i];
        atomicAdd(&dl[(e.x >> 20) & 63], __int_as_float(e.y));
    }
    int m = *ovf_cnt; if (m > OVCAP) m = OVCAP;   // normally 0
    for (int i = t; i < m; i += 256) {
        int d = ovd[i];
        if ((d >> BINSH) == b) atomicAdd(&dl[d & 63], ovw[i]);
    }
    __syncthreads();
    int n = b * 64 + t;
    if (t < 64 && n < N) {
        float d = dl[t];
        deg[n] = d;
        dinv[n] = d > 0.f ? rsqrtf(d) : 0.f;
    }
}

// ---------- 5. FUSED gather(bf16 xm) + head epilogue ----------
__global__ __launch_bounds__(256) void k_gf(
    const unsigned short* __restrict__ xm, const float* __restrict__ dinv,
    const int* __restrict__ gcnt, const int2* __restrict__ part,
    const float* __restrict__ projB, const float* __restrict__ linW,
    const float* __restrict__ linB, const int* __restrict__ ovf_cnt,
    const int* __restrict__ ovs, const int* __restrict__ ovd,
    const float* __restrict__ ovw, float* __restrict__ out, int N) {
    __shared__ int  lcnt[64];
    __shared__ int  loff[65];
    __shared__ int  lcur[64];
    __shared__ int2 ledge[BCAP];   // {src | nl<<20, dinv[src]*ew}
    __shared__ float pbs[64], lws[64];
    int t = threadIdx.x, b = blockIdx.x;
    if (t < 64) { lcnt[t] = 0; pbs[t] = projB[t]; lws[t] = linW[t]; }
    __syncthreads();
    int c = gcnt[b]; if (c > BCAP) c = BCAP;
    const int2* pe = part + (size_t)b * BCAP;
    for (int i = t; i < c; i += 256) {
        atomicAdd(&lcnt[(pe[i].x >> 20) & 63], 1);
    }
    __syncthreads();
    if (t == 0) {
        int o = 0;
#pragma unroll 16
        for (int k = 0; k < 64; k++) { loff[k] = o; o += lcnt[k]; }
        loff[64] = o;
    }
    __syncthreads();
    if (t < 64) lcur[t] = loff[t];
    __syncthreads();
    // reorder + premultiply dinv[src] (streaming phase absorbs the random dinv read)
    for (int i = t; i < c; i += 256) {
        int2 e = pe[i];
        int s = e.x & 0xFFFFF;
        float nw = dinv[s] * __int_as_float(e.y);
        int p = atomicAdd(&lcur[(e.x >> 20) & 63], 1);
        ledge[p] = make_int2(e.x, __float_as_int(nw));
    }
    __syncthreads();
    int m = *ovf_cnt; if (m > OVCAP) m = OVCAP;   // normally 0
    float lb = linB[0];
    int wv = t >> 6, lane = t & 63, eg = lane >> 4, fq = lane & 15, f = fq * 4;
    for (int nl = wv; nl < 64; nl += 4) {
        int n = b * 64 + nl;
        if (n >= N) continue;
        float dn = dinv[n];
        int beg = loff[nl], end = loff[nl + 1];
        float ax = 0.f, ay = 0.f, az = 0.f, aw = 0.f;
        float bx = 0.f, by = 0.f, bz = 0.f, bw = 0.f;
        int i = beg + eg;
        for (; i + 4 < end; i += 8) {      // 2 independent bf16 row loads in flight
            int2 e0 = ledge[i];
            int2 e1 = ledge[i + 4];
            int s0 = e0.x & 0xFFFFF, s1 = e1.x & 0xFFFFF;
            uint2 u0 = *(const uint2*)&xm[(size_t)s0 * 64 + f];
            uint2 u1 = *(const uint2*)&xm[(size_t)s1 * 64 + f];
            float nm0 = __int_as_float(e0.y);
            float nm1 = __int_as_float(e1.y);
            ax += nm0 * bf2f(u0.x);       ay += nm0 * bf2f(u0.x >> 16);
            az += nm0 * bf2f(u0.y);       aw += nm0 * bf2f(u0.y >> 16);
            bx += nm1 * bf2f(u1.x);       by += nm1 * bf2f(u1.x >> 16);
            bz += nm1 * bf2f(u1.y);       bw += nm1 * bf2f(u1.y >> 16);
        }
        for (; i < end; i += 4) {
            int2 e = ledge[i];
            int s = e.x & 0xFFFFF;
            float nm = __int_as_float(e.y);
            uint2 u = *(const uint2*)&xm[(size_t)s * 64 + f];
            ax += nm * bf2f(u.x); ay += nm * bf2f(u.x >> 16);
            az += nm * bf2f(u.y); aw += nm * bf2f(u.y >> 16);
        }
        ax += bx; ay += by; az += bz; aw += bw;
        ax *= dn; ay *= dn; az *= dn; aw *= dn;
        // reduce the 4 edge-groups FIRST (self-loop must be added once, after)
        ax += __shfl_xor(ax, 16); ay += __shfl_xor(ay, 16);
        az += __shfl_xor(az, 16); aw += __shfl_xor(aw, 16);
        ax += __shfl_xor(ax, 32); ay += __shfl_xor(ay, 32);
        az += __shfl_xor(az, 32); aw += __shfl_xor(aw, 32);
        if (eg == 0) {
            // self-loop (exactly once, post-reduction)
            {
                uint2 u = *(const uint2*)&xm[(size_t)n * 64 + f];
                float sl = dn * dn;
                ax += sl * bf2f(u.x); ay += sl * bf2f(u.x >> 16);
                az += sl * bf2f(u.y); aw += sl * bf2f(u.y >> 16);
            }
            // ovf patch for this node (normally m==0)
            for (int q = 0; q < m; q++) {
                if (ovd[q] == n) {
                    int s = ovs[q];
                    float nm = dinv[s] * ovw[q] * dn;
                    uint2 u = *(const uint2*)&xm[(size_t)s * 64 + f];
                    ax += nm * bf2f(u.x); ay += nm * bf2f(u.x >> 16);
                    az += nm * bf2f(u.y); aw += nm * bf2f(u.y >> 16);
                }
            }
            // head epilogue: s = sum_f relu(aggm[f]+pb[f])*lW[f]
            float v0 = ax + pbs[f],     v1 = ay + pbs[f + 1];
            float v2 = az + pbs[f + 2], v3 = aw + pbs[f + 3];
            float s = (v0 > 0.f ? v0 : 0.f) * lws[f]
                    + (v1 > 0.f ? v1 : 0.f) * lws[f + 1]
                    + (v2 > 0.f ? v2 : 0.f) * lws[f + 2]
                    + (v3 > 0.f ? v3 : 0.f) * lws[f + 3];
            s += __shfl_xor(s, 1); s += __shfl_xor(s, 2);
            s += __shfl_xor(s, 4); s += __shfl_xor(s, 8);
            if (fq == 0) out[n] = s + lb;
        }
    }
}

extern "C" void kernel_launch(void* const* d_in, const int* in_sizes, int n_in,
                              void* d_out, int out_size, void* d_ws, size_t ws_size,
                              hipStream_t stream) {
    const float* x   = (const float*)d_in[0];
    const int*   ei  = (const int*)d_in[1];
    const float* ew  = (const float*)d_in[2];
    const float* W0  = (const float*)d_in[3];
    const float* gWi = (const float*)d_in[4];
    const float* gWh = (const float*)d_in[5];
    const float* gbi = (const float*)d_in[6];
    const float* gbh = (const float*)d_in[7];
    const float* pW  = (const float*)d_in[8];
    const float* pb  = (const float*)d_in[9];
    const float* lW  = (const float*)d_in[10];
    const float* lb  = (const float*)d_in[11];
    float* out = (float*)d_out;

    static const int EXPSZ[12] = {6400000, 3200000, 1600000, 4096, 12288, 12288,
                                  192, 192, 4096, 64, 64, 1};
    int mism = -1;
    for (int i = 0; i < 12 && i < n_in; i++)
        if (in_sizes[i] != EXPSZ[i]) { mism = i; break; }
    if (mism >= 0) {
        k_sentinel<<<(out_size + 255) / 256, 256, 0, stream>>>(out, out_size,
                                                               ldexpf(1.f, 30 + 3 * mism));
        return;
    }

    int N = in_sizes[0] / FDIM;          // 100000
    int E = in_sizes[1] / 2;             // 1600000
    const int* src = ei;
    const int* dst = ei + E;

    // ws layout (bytes):
    //  0     M 16 KB
    //  32K   gcnt 6.3 KB | 39K ovf_cnt 4 B     (zeroed by k_evolveM)
    //  44K   ovs 32 KB | 76K ovd 32 KB | 108K ovw 32 KB
    //  512K  deg 400 KB | 1M dinv 400 KB | 2M part 19.2 MB | 22M xm 12.8 MB
    char* wsb = (char*)d_ws;
    float* M       = (float*)(wsb);
    int*   gcnt    = (int*)  (wsb + (32u << 10));
    int*   ovf_cnt = (int*)  (wsb + (39u << 10));
    int*   ovs     = (int*)  (wsb + (44u << 10));
    int*   ovd     = (int*)  (wsb + (76u << 10));
    float* ovw     = (float*)(wsb + (108u << 10));
    float* deg     = (float*)(wsb + (512u << 10));
    float* dinv    = (float*)(wsb + (1u << 20));
    int2*  part    = (int2*) (wsb + (2u << 20));
    unsigned short* xm = (unsigned short*)(wsb + (22u << 20));

    k_evolveM<<<64, 64, 0, stream>>>(W0, gWi, gWh, gbi, gbh, pW, M, gcnt, ovf_cnt);
    k_xm<<<NBINS, 256, 0, stream>>>(x, M, xm, N);
    k_part<<<(E + PSTAGE - 1) / PSTAGE, 1024, 0, stream>>>(src, dst, ew, gcnt, part,
                                                           ovf_cnt, ovs, ovd, ovw, E);
    k_deg2<<<NBINS, 256, 0, stream>>>(gcnt, part, ovf_cnt, ovd, ovw, deg, dinv, N);
    k_gf<<<NBINS, 256, 0, stream>>>(xm, dinv, gcnt, part, pb, lW, lb,
                                    ovf_cnt, ovs, ovd, ovw, out, N);
}

// Round 22
// 193.412 us; speedup vs baseline: 1.3952x; 1.0129x over previous
//
#include <hip/hip_runtime.h>
#include <stdint.h>

#define FDIM 64
#define BINSH 6
#define NBINS 1563         // ceil(100000 / 64)
#define BCAP 1536          // bin capacity; mean 1024, sigma ~32 -> 16 sigma margin
#define OVCAP 8192         // overflow-edge capacity (expected usage: 0)
#define PSTAGE 8192        // edges per partition block
#define PBLK 196           // ceil(E / PSTAGE)
#define LSTRIDE 72         // loffg row stride (ints)

__device__ __forceinline__ float bf2f(unsigned int u) {
    union { float f; uint32_t i; } v; v.i = (u & 0xFFFFu) << 16; return v.f;
}
__device__ __forceinline__ unsigned short f2bf(float f) {
    union { float f; uint32_t i; } v; v.f = f;
    uint32_t u = v.i;
    u += 0x7FFFu + ((u >> 16) & 1u);   // RNE
    return (unsigned short)(u >> 16);
}

// ---------- sentinel ----------
__global__ __launch_bounds__(256) void k_sentinel(float* out, int N, float val) {
    int n = blockIdx.x * 256 + threadIdx.x;
    if (n < N) out[n] = (n == 0) ? val : 0.f;
}

// ---------- K1: blocks [0,PBLK) partition edges ; blocks [PBLK,PBLK+64) GRU->M ----------
__global__ __launch_bounds__(1024) void k_prep(
    const int* __restrict__ src, const int* __restrict__ dst,
    const float* __restrict__ ew, int* __restrict__ gcnt,
    int2* __restrict__ part, int* __restrict__ ovf_cnt,
    int* __restrict__ ovs, int* __restrict__ ovd, float* __restrict__ ovw, int E,
    const float* __restrict__ W0, const float* __restrict__ Wi,
    const float* __restrict__ Wh, const float* __restrict__ bi,
    const float* __restrict__ bh, const float* __restrict__ projW,
    float* __restrict__ M) {
    __shared__ char sm[12504];   // part: hist+lcur (2*NBINS ints); evolve: 128 floats
    int t = threadIdx.x;
    if (blockIdx.x < PBLK) {
        // ---- edge partition (no sort): LDS histogram -> block-run reservation ----
        int* hist = (int*)sm;
        int* lcur = hist + NBINS;
        for (int b = t; b < NBINS; b += 1024) hist[b] = 0;
        __syncthreads();
        int e0 = blockIdx.x * PSTAGE;
        int cnt = E - e0; if (cnt > PSTAGE) cnt = PSTAGE;
        for (int i = t; i < cnt; i += 1024) atomicAdd(&hist[dst[e0 + i] >> BINSH], 1);
        __syncthreads();
        for (int b = t; b < NBINS; b += 1024) {
            int h = hist[b];
            lcur[b] = h ? atomicAdd(&gcnt[b], h) : 0;
        }
        __syncthreads();
        for (int i = t; i < cnt; i += 1024) {
            int e = e0 + i;
            int d = dst[e];
            int b = d >> BINSH;
            int p = atomicAdd(&lcur[b], 1);
            if (p < BCAP) {
                part[(size_t)b * BCAP + p] = make_int2(src[e] | ((d & 63) << 20),
                                                       __float_as_int(ew[e]));
            } else {
                int op = atomicAdd(ovf_cnt, 1);
                if (op < OVCAP) {
                    ovs[op] = src[e];
                    ovd[op] = d;
                    ovw[op] = ew[e];
                }
            }
        }
    } else {
        // ---- GRU evolve row i -> M row i (W stays in LDS) ----
        int i = blockIdx.x - PBLK;
        float* w0s  = (float*)sm;
        float* wrow = w0s + 64;
        if (t < 64) w0s[t] = W0[i * 64 + t];
        __syncthreads();
        if (t < 64) {
            int j = t;
            float a0 = 0.f, a1 = 0.f, a2 = 0.f, b0 = 0.f, b1 = 0.f, b2 = 0.f;
#pragma unroll 8
            for (int k = 0; k < 64; k++) {
                float w0k = w0s[k];
                a0 += w0k * Wi[(j)       * 64 + k];
                a1 += w0k * Wi[(64 + j)  * 64 + k];
                a2 += w0k * Wi[(128 + j) * 64 + k];
                b0 += w0k * Wh[(j)       * 64 + k];
                b1 += w0k * Wh[(64 + j)  * 64 + k];
                b2 += w0k * Wh[(128 + j) * 64 + k];
            }
            float ir = a0 + bi[j],        hr = b0 + bh[j];
            float iz = a1 + bi[64 + j],   hz = b1 + bh[64 + j];
            float in_ = a2 + bi[128 + j], hn = b2 + bh[128 + j];
            float r = 1.f / (1.f + expf(-(ir + hr)));
            float z = 1.f / (1.f + expf(-(iz + hz)));
            float n = tanhf(in_ + r * hn);
            wrow[j] = (1.f - z) * n + z * w0s[j];
        }
        __syncthreads();
        if (t < 64) {
            float s = 0.f;
#pragma unroll 8
            for (int q = 0; q < 64; q++) s += wrow[q] * projW[t * 64 + q];
            M[i * 64 + t] = s;
        }
    }
}

// ---------- K2: blocks [0,NBINS) xm = bf16(x@M) ; blocks [NBINS,2*NBINS) deg+dinv+loff ----------
__global__ __launch_bounds__(256) void k_xmdeg(
    const float* __restrict__ x, const float* __restrict__ M,
    unsigned short* __restrict__ xm, int N,
    const int* __restrict__ gcnt, const int2* __restrict__ part,
    const int* __restrict__ ovf_cnt, const int* __restrict__ ovd,
    const float* __restrict__ ovw, float* __restrict__ dinv,
    int* __restrict__ loffg) {
    __shared__ char sm[34816];
    int t = threadIdx.x;
    if (blockIdx.x < NBINS) {
        // ---- xm tile GEMM ----
        float* xs = (float*)sm;
        float* ms = xs + 64 * 68;
        int nb = blockIdx.x * 64;
#pragma unroll
        for (int i = 0; i < 4; i++) {
            int lin = i * 1024 + t * 4;
            int row = lin >> 6, col = lin & 63;
            int node = nb + row;
            float4 v = make_float4(0.f, 0.f, 0.f, 0.f);
            if (node < N) v = *(const float4*)(x + (size_t)node * 64 + col);
            *(float4*)&xs[row * 68 + col] = v;
            *(float4*)&ms[row * 68 + col] = *(const float4*)(M + lin);
        }
        __syncthreads();
        int tj = t & 15, tn = t >> 4;
        float acc[4][4] = {};
        for (int k = 0; k < 64; k += 4) {
            float4 xv[4], mv[4];
#pragma unroll
            for (int nn = 0; nn < 4; nn++) xv[nn] = *(const float4*)&xs[(tn * 4 + nn) * 68 + k];
#pragma unroll
            for (int kk = 0; kk < 4; kk++) mv[kk] = *(const float4*)&ms[(k + kk) * 68 + tj * 4];
#pragma unroll
            for (int nn = 0; nn < 4; nn++) {
                const float* xp = (const float*)&xv[nn];
#pragma unroll
                for (int kk = 0; kk < 4; kk++) {
                    float xk = xp[kk];
                    const float* mp = (const float*)&mv[kk];
                    acc[nn][0] += xk * mp[0];
                    acc[nn][1] += xk * mp[1];
                    acc[nn][2] += xk * mp[2];
                    acc[nn][3] += xk * mp[3];
                }
            }
        }
#pragma unroll
        for (int nn = 0; nn < 4; nn++) {
            int node = nb + tn * 4 + nn;
            if (node < N) {
                ushort4 o;
                o.x = f2bf(acc[nn][0]); o.y = f2bf(acc[nn][1]);
                o.z = f2bf(acc[nn][2]); o.w = f2bf(acc[nn][3]);
                *(ushort4*)&xm[(size_t)node * 64 + tj * 4] = o;
            }
        }
    } else {
        // ---- deg + dinv + per-bin CSR offsets ----
        int b = blockIdx.x - NBINS;
        float* dl   = (float*)sm;          // 64
        int*   cntl = (int*)(dl + 64);     // 64
        int*   lofl = cntl + 64;           // 65
        if (t < 64) { dl[t] = 1.0f; cntl[t] = 0; }
        __syncthreads();
        int c = gcnt[b]; if (c > BCAP) c = BCAP;
        const int2* pe = part + (size_t)b * BCAP;
        for (int i = t; i < c; i += 256) {
            int2 e = pe[i];
            int nl = (e.x >> 20) & 63;
            atomicAdd(&dl[nl], __int_as_float(e.y));
            atomicAdd(&cntl[nl], 1);
        }
        int m = *ovf_cnt; if (m > OVCAP) m = OVCAP;   // normally 0
        for (int i = t; i < m; i += 256) {
            int d = ovd[i];
            if ((d >> BINSH) == b) atomicAdd(&dl[d & 63], ovw[i]);
        }
        __syncthreads();
        if (t == 0) {
            int o = 0;
#pragma unroll 16
            for (int k = 0; k < 64; k++) { lofl[k] = o; o += cntl[k]; }
            lofl[64] = o;
        }
        __syncthreads();
        if (t < 64) {
            int n = b * 64 + t;
            if (n < N) dinv[n] = rsqrtf(dl[t]);   // dl >= 1 always
        }
        if (t < 65) loffg[b * LSTRIDE + t] = lofl[t];
    }
}

// ---------- K3: FUSED gather(bf16 xm) + head epilogue ----------
__global__ __launch_bounds__(256) void k_gf(
    const unsigned short* __restrict__ xm, const float* __restrict__ dinv,
    const int* __restrict__ gcnt, const int2* __restrict__ part,
    const int* __restrict__ loffg,
    const float* __restrict__ projB, const float* __restrict__ linW,
    const float* __restrict__ linB, const int* __restrict__ ovf_cnt,
    const int* __restrict__ ovs, const int* __restrict__ ovd,
    const float* __restrict__ ovw, float* __restrict__ out, int N) {
    __shared__ int  loff[65];
    __shared__ int  lcur[64];
    __shared__ int2 ledge[BCAP];   // {src | nl<<20, dinv[src]*ew}
    __shared__ float pbs[64], lws[64];
    int t = threadIdx.x, b = blockIdx.x;
    if (t < 65) loff[t] = loffg[b * LSTRIDE + t];
    if (t < 64) { pbs[t] = projB[t]; lws[t] = linW[t]; }
    __syncthreads();
    if (t < 64) lcur[t] = loff[t];
    __syncthreads();
    int c = gcnt[b]; if (c > BCAP) c = BCAP;
    const int2* pe = part + (size_t)b * BCAP;
    // reorder + premultiply dinv[src] (streaming phase absorbs the random dinv read)
    for (int i = t; i < c; i += 256) {
        int2 e = pe[i];
        int s = e.x & 0xFFFFF;
        float nw = dinv[s] * __int_as_float(e.y);
        int p = atomicAdd(&lcur[(e.x >> 20) & 63], 1);
        ledge[p] = make_int2(e.x, __float_as_int(nw));
    }
    __syncthreads();
    int m = *ovf_cnt; if (m > OVCAP) m = OVCAP;   // normally 0
    float lb = linB[0];
    int wv = t >> 6, lane = t & 63, eg = lane >> 4, fq = lane & 15, f = fq * 4;
    for (int nl = wv; nl < 64; nl += 4) {
        int n = b * 64 + nl;
        if (n >= N) continue;
        float dn = dinv[n];
        int beg = loff[nl], end = loff[nl + 1];
        float ax = 0.f, ay = 0.f, az = 0.f, aw = 0.f;
        float bx = 0.f, by = 0.f, bz = 0.f, bw = 0.f;
        int i = beg + eg;
        for (; i + 4 < end; i += 8) {      // 2 independent bf16 row loads in flight
            int2 e0 = ledge[i];
            int2 e1 = ledge[i + 4];
            int s0 = e0.x & 0xFFFFF, s1 = e1.x & 0xFFFFF;
            uint2 u0 = *(const uint2*)&xm[(size_t)s0 * 64 + f];
            uint2 u1 = *(const uint2*)&xm[(size_t)s1 * 64 + f];
            float nm0 = __int_as_float(e0.y);
            float nm1 = __int_as_float(e1.y);
            ax += nm0 * bf2f(u0.x);       ay += nm0 * bf2f(u0.x >> 16);
            az += nm0 * bf2f(u0.y);       aw += nm0 * bf2f(u0.y >> 16);
            bx += nm1 * bf2f(u1.x);       by += nm1 * bf2f(u1.x >> 16);
            bz += nm1 * bf2f(u1.y);       bw += nm1 * bf2f(u1.y >> 16);
        }
        for (; i < end; i += 4) {
            int2 e = ledge[i];
            int s = e.x & 0xFFFFF;
            float nm = __int_as_float(e.y);
            uint2 u = *(const uint2*)&xm[(size_t)s * 64 + f];
            ax += nm * bf2f(u.x); ay += nm * bf2f(u.x >> 16);
            az += nm * bf2f(u.y); aw += nm * bf2f(u.y >> 16);
        }
        ax += bx; ay += by; az += bz; aw += bw;
        ax *= dn; ay *= dn; az *= dn; aw *= dn;
        // reduce the 4 edge-groups FIRST (self-loop added once, after)
        ax += __shfl_xor(ax, 16); ay += __shfl_xor(ay, 16);
        az += __shfl_xor(az, 16); aw += __shfl_xor(aw, 16);
        ax += __shfl_xor(ax, 32); ay += __shfl_xor(ay, 32);
        az += __shfl_xor(az, 32); aw += __shfl_xor(aw, 32);
        if (eg == 0) {
            // self-loop (exactly once, post-reduction)
            {
                uint2 u = *(const uint2*)&xm[(size_t)n * 64 + f];
                float sl = dn * dn;
                ax += sl * bf2f(u.x); ay += sl * bf2f(u.x >> 16);
                az += sl * bf2f(u.y); aw += sl * bf2f(u.y >> 16);
            }
            // ovf patch for this node (normally m==0)
            for (int q = 0; q < m; q++) {
                if (ovd[q] == n) {
                    int s = ovs[q];
                    float nm = dinv[s] * ovw[q] * dn;
                    uint2 u = *(const uint2*)&xm[(size_t)s * 64 + f];
                    ax += nm * bf2f(u.x); ay += nm * bf2f(u.x >> 16);
                    az += nm * bf2f(u.y); aw += nm * bf2f(u.y >> 16);
                }
            }
            // head epilogue: s = sum_f relu(aggm[f]+pb[f])*lW[f]
            float v0 = ax + pbs[f],     v1 = ay + pbs[f + 1];
            float v2 = az + pbs[f + 2], v3 = aw + pbs[f + 3];
            float s = (v0 > 0.f ? v0 : 0.f) * lws[f]
                    + (v1 > 0.f ? v1 : 0.f) * lws[f + 1]
                    + (v2 > 0.f ? v2 : 0.f) * lws[f + 2]
                    + (v3 > 0.f ? v3 : 0.f) * lws[f + 3];
            s += __shfl_xor(s, 1); s += __shfl_xor(s, 2);
            s += __shfl_xor(s, 4); s += __shfl_xor(s, 8);
            if (fq == 0) out[n] = s + lb;
        }
    }
}

extern "C" void kernel_launch(void* const* d_in, const int* in_sizes, int n_in,
                              void* d_out, int out_size, void* d_ws, size_t ws_size,
                              hipStream_t stream) {
    const float* x   = (const float*)d_in[0];
    const int*   ei  = (const int*)d_in[1];
    const float* ew  = (const float*)d_in[2];
    const float* W0  = (const float*)d_in[3];
    const float* gWi = (const float*)d_in[4];
    const float* gWh = (const float*)d_in[5];
    const float* gbi = (const float*)d_in[6];
    const float* gbh = (const float*)d_in[7];
    const float* pW  = (const float*)d_in[8];
    const float* pb  = (const float*)d_in[9];
    const float* lW  = (const float*)d_in[10];
    const float* lb  = (const float*)d_in[11];
    float* out = (float*)d_out;

    static const int EXPSZ[12] = {6400000, 3200000, 1600000, 4096, 12288, 12288,
                                  192, 192, 4096, 64, 64, 1};
    int mism = -1;
    for (int i = 0; i < 12 && i < n_in; i++)
        if (in_sizes[i] != EXPSZ[i]) { mism = i; break; }
    if (mism >= 0) {
        k_sentinel<<<(out_size + 255) / 256, 256, 0, stream>>>(out, out_size,
                                                               ldexpf(1.f, 30 + 3 * mism));
        return;
    }

    int N = in_sizes[0] / FDIM;          // 100000
    int E = in_sizes[1] / 2;             // 1600000
    const int* src = ei;
    const int* dst = ei + E;

    // ws layout (bytes):
    //  0     M 16 KB
    //  32K   gcnt 6.3 KB | 39K ovf_cnt 4 B   (memset 32K..40K)
    //  44K   ovs 32 KB | 76K ovd 32 KB | 108K ovw 32 KB
    //  1M    dinv 400 KB | 1.5M loffg 450 KB | 2M part 19.2 MB | 22M xm 12.8 MB
    char* wsb = (char*)d_ws;
    float* M       = (float*)(wsb);
    int*   gcnt    = (int*)  (wsb + (32u << 10));
    int*   ovf_cnt = (int*)  (wsb + (39u << 10));
    int*   ovs     = (int*)  (wsb + (44u << 10));
    int*   ovd     = (int*)  (wsb + (76u << 10));
    float* ovw     = (float*)(wsb + (108u << 10));
    float* dinv    = (float*)(wsb + (1u << 20));
    int*   loffg   = (int*)  (wsb + 1572864u);
    int2*  part    = (int2*) (wsb + (2u << 20));
    unsigned short* xm = (unsigned short*)(wsb + (22u << 20));

    hipMemsetAsync(gcnt, 0, (8u << 10), stream);   // zeroes gcnt + ovf_cnt

    k_prep<<<PBLK + 64, 1024, 0, stream>>>(src, dst, ew, gcnt, part,
                                           ovf_cnt, ovs, ovd, ovw, E,
                                           W0, gWi, gWh, gbi, gbh, pW, M);
    k_xmdeg<<<NBINS * 2, 256, 0, stream>>>(x, M, xm, N, gcnt, part,
                                           ovf_cnt, ovd, ovw, dinv, loffg);
    k_gf<<<NBINS, 256, 0, stream>>>(xm, dinv, gcnt, part, loffg, pb, lW, lb,
                                    ovf_cnt, ovs, ovd, ovw, out, N);
}